// Round 6
// baseline (250.255 us; speedup 1.0000x reference)
//
#include <hip/hip_runtime.h>
#include <math.h>

#define NB 16384
#define LH 50
#define D  64

// workspace layout (bytes):
//   0       : wsh  (f16 weight frags, 3 sections x 4096 halves = 24 KB)
//   49152   : tbf  (f32: b2p[64] ba2p[64] wa3p[64] | R1h f16[5][64] @ f32-idx 192)
//   65536   : UB   (f32 [16384][64] permuted, u@A1up + ba1, per node)
//   4259840 : P1h  (f16 [100000][64] permuted slot order, v2e@W1_top)
#define TBF_OFF 49152
#define UB_OFF  65536
#define P1_OFF  4259840

typedef _Float16 half2v __attribute__((ext_vector_type(2)));
typedef _Float16 half8  __attribute__((ext_vector_type(8)));
typedef float    f32x16 __attribute__((ext_vector_type(16)));
typedef unsigned int u32;

#define MFMA(a, b, c) __builtin_amdgcn_mfma_f32_32x32x16_f16((a), (b), (c), 0, 0, 0)

// ---- fragment facts (32x32x16, verified) ----
// A[m][k]: m=lane&31, k=(lane>>5)*8+j (8 contiguous k per lane)
// B[k][n]: n=lane&31, k=(lane>>5)*8+j
// C/D:     col=lane&31, row=(reg&3)+8*(reg>>2)+4*(lane>>5)
// permuted slot t(hv,mt,q) = hv*32+mt*16+q <-> feat = mt*32+(q&3)+8*(q>>2)+4*hv

__device__ __forceinline__ u32 pack2(float a, float b) {
    half2v h; h[0] = (_Float16)a; h[1] = (_Float16)b;
    return __builtin_bit_cast(u32, h);
}
__device__ __forceinline__ half8 mk8(u32 a, u32 b, u32 c, u32 d) {
    uint4 t = make_uint4(a, b, c, d);
    return __builtin_bit_cast(half8, t);
}
__device__ __forceinline__ half8 cvt8(const float* __restrict__ p) {
    float4 u = *(const float4*)p;
    float4 v = *(const float4*)(p + 4);
    return mk8(pack2(u.x, u.y), pack2(u.z, u.w), pack2(v.x, v.y), pack2(v.z, v.w));
}
// f16 add + relu (compiles to v_pk_add_f16 / v_pk_max_f16)
__device__ __forceinline__ half8 addrelu8(half8 a, half8 r) {
    half8 s = a + r;
    #pragma unroll
    for (int j = 0; j < 8; ++j) s[j] = s[j] > (_Float16)0 ? s[j] : (_Float16)0;
    return s;
}

// relu + f16-pack + lane^32 exchange: one C tile -> two B-frags (k-halves)
__device__ __forceinline__ void xform_tile(const f32x16& t, int hv, half8& f0, half8& f1) {
    u32 p[8], rp[8];
    #pragma unroll
    for (int q = 0; q < 8; ++q) p[q] = pack2(fmaxf(t[2*q], 0.f), fmaxf(t[2*q+1], 0.f));
    #pragma unroll
    for (int q = 0; q < 8; ++q) rp[q] = (u32)__shfl_xor((int)p[q], 32, 64);
    f0 = hv ? mk8(rp[2], rp[3], p[2], p[3]) : mk8(p[0], p[1], rp[0], rp[1]);
    f1 = hv ? mk8(rp[6], rp[7], p[6], p[7]) : mk8(p[4], p[5], rp[4], rp[5]);
}

// bias/UB tile from a 64-float permuted row (works for LDS or global pointers)
__device__ __forceinline__ f32x16 ldbias(const float* tb, int hv, int mt) {
    const float4* p = (const float4*)tb + hv*8 + mt*4;
    f32x16 r;
    #pragma unroll
    for (int q = 0; q < 4; ++q) {
        float4 v = p[q];
        r[4*q] = v.x; r[4*q+1] = v.y; r[4*q+2] = v.z; r[4*q+3] = v.w;
    }
    return r;
}

// build an A-frag of a 64x64 row-major f32 weight W on the fly (L1/L2-hot)
__device__ __forceinline__ half8 mkw(const float* __restrict__ W, int ks, int mt,
                                     int hv, int m) {
    half8 r;
    #pragma unroll
    for (int j = 0; j < 8; ++j)
        r[j] = (_Float16)W[(ks*16 + hv*8 + j)*64 + mt*32 + m];
    return r;
}

// ================= K1: ALL prep in one launch (block-range partitioned) ========
// blocks [0,782)   : P1h = f16(v2e @ W1_top)   (w1-top frags converted inline)
// blocks [782,910) : UB  = u2e[nodes]@A1up+ba1 (wa1-up frags converted inline)
// blocks [910,958) : wsh sections 0..2 (w2 pi-folded, wa1low, wa2)
// block  958       : tbf tables b2p/ba2p/wa3p
// block  959       : R1h[5][64] f16 (rating rows through layer1, f32 math)
__global__ __launch_bounds__(256) void prep_all(
    const int*   __restrict__ nodes,
    const float* __restrict__ v2e, const float* __restrict__ u2e,
    const float* __restrict__ r2e,
    const float* __restrict__ w1,  const float* __restrict__ b1,
    const float* __restrict__ w2,  const float* __restrict__ b2,
    const float* __restrict__ wa1, const float* __restrict__ ba1,
    const float* __restrict__ wa2, const float* __restrict__ ba2,
    const float* __restrict__ wa3,
    _Float16* __restrict__ wsh, float* __restrict__ tbf,
    float* __restrict__ UB, _Float16* __restrict__ P1h) {
    const int blk = blockIdx.x;
    const int lane = threadIdx.x & 63;
    const int n = lane & 31, hv = lane >> 5;

    if (blk < 782) {                               // ---- P1h tiles (f16 rows)
        const int tile = blk*4 + (threadIdx.x >> 6);
        if (tile >= 3125) return;
        const int item = tile*32 + n;
        half8 bf[4];
        #pragma unroll
        for (int ks = 0; ks < 4; ++ks)
            bf[ks] = cvt8(v2e + (size_t)item*64 + ks*16 + hv*8);
        f32x16 a0, a1;
        #pragma unroll
        for (int q = 0; q < 16; ++q) { a0[q] = 0.f; a1[q] = 0.f; }
        #pragma unroll
        for (int ks = 0; ks < 4; ++ks) {
            a0 = MFMA(mkw(w1, ks, 0, hv, n), bf[ks], a0);
            a1 = MFMA(mkw(w1, ks, 1, hv, n), bf[ks], a1);
        }
        u32 dw[16];
        #pragma unroll
        for (int q = 0; q < 8; ++q) dw[q]     = pack2(a0[2*q], a0[2*q+1]);
        #pragma unroll
        for (int q = 0; q < 8; ++q) dw[8 + q] = pack2(a1[2*q], a1[2*q+1]);
        uint4* dst = (uint4*)(P1h + (size_t)item*64 + hv*32);
        dst[0] = make_uint4(dw[0],  dw[1],  dw[2],  dw[3]);
        dst[1] = make_uint4(dw[4],  dw[5],  dw[6],  dw[7]);
        dst[2] = make_uint4(dw[8],  dw[9],  dw[10], dw[11]);
        dst[3] = make_uint4(dw[12], dw[13], dw[14], dw[15]);
        return;
    }
    if (blk < 910) {                               // ---- UB tiles
        const int tile = (blk - 782)*4 + (threadIdx.x >> 6);   // 512 tiles exactly
        const int s = tile*32 + n;
        const int nid = nodes[s];
        half8 bf[4];
        #pragma unroll
        for (int ks = 0; ks < 4; ++ks)
            bf[ks] = cvt8(u2e + (size_t)nid*64 + ks*16 + hv*8);
        f32x16 a0, a1;
        #pragma unroll
        for (int q = 0; q < 16; ++q) {
            a0[q] = ba1[(q & 3) + 8*(q >> 2) + 4*hv];
            a1[q] = ba1[32 + (q & 3) + 8*(q >> 2) + 4*hv];
        }
        const float* wup = wa1 + 64*64;            // wa1 upper half rows
        #pragma unroll
        for (int ks = 0; ks < 4; ++ks) {
            a0 = MFMA(mkw(wup, ks, 0, hv, n), bf[ks], a0);
            a1 = MFMA(mkw(wup, ks, 1, hv, n), bf[ks], a1);
        }
        float4* dst = (float4*)(UB + (size_t)s*64 + hv*32);
        #pragma unroll
        for (int q = 0; q < 4; ++q) {
            dst[q]     = make_float4(a0[4*q], a0[4*q+1], a0[4*q+2], a0[4*q+3]);
            dst[4 + q] = make_float4(a1[4*q], a1[4*q+1], a1[4*q+2], a1[4*q+3]);
        }
        return;
    }
    if (blk < 958) {                               // ---- wsh sections 0..2
        const int idx = (blk - 910)*256 + threadIdx.x;         // [0, 12288)
        const int j = idx & 7, l2 = (idx >> 3) & 63;
        const int hv2 = l2 >> 5, m31 = l2 & 31;
        const int f = (idx >> 9) & 7, ks = f & 3, mt = f >> 2;
        const int sec = idx >> 12;
        const int tau = ks*16 + hv2*8 + j;
        float v;
        if (sec == 0) {       // w2 with k-permutation folded in
            const int thv = (tau >> 5) & 1, tmt = (tau >> 4) & 1, i = tau & 15;
            const int feat = tmt*32 + (i & 3) + 8*(i >> 2) + 4*thv;
            v = w2[feat*64 + mt*32 + m31];
        }
        else if (sec == 1) v = wa1[tau*64 + mt*32 + m31];
        else               v = wa2[tau*64 + mt*32 + m31];
        wsh[idx] = (_Float16)v;
        return;
    }
    if (blk == 958) {                              // ---- tbf tables
        if (threadIdx.x < 64) {
            const int t = threadIdx.x;
            const int thv = t >> 5, r = t & 31, mtt = r >> 4, i = r & 15;
            const int feat = mtt*32 + (i & 3) + 8*(i >> 2) + 4*thv;
            tbf[t]       = b2[feat];
            tbf[64 + t]  = ba2[feat];
            tbf[128 + t] = wa3[feat];
        }
        return;
    }
    {                                              // ---- blk 959: R1h (f16)
        _Float16* R1h = (_Float16*)(tbf + 192);
        #pragma unroll 1
        for (int base = 0; base < 320; base += 256) {
            const int o = base + (int)threadIdx.x;
            if (o < 320) {
                const int rr = o >> 6, tt = o & 63;
                const int thv = tt >> 5, r5 = tt & 31, mtt = r5 >> 4, i = r5 & 15;
                const int feat = mtt*32 + (i & 3) + 8*(i >> 2) + 4*thv;
                float acc = b1[feat];
                for (int k = 0; k < 64; ++k)
                    acc += r2e[rr*64 + k] * w1[(64 + k)*64 + feat];
                R1h[rr*64 + tt] = (_Float16)acc;
            }
        }
    }
}

// ================= K2: fused forward — weights in LDS, direct B-frag gather ====
// Theory: wsh (24 KB) was being thrashed out of L1 by the per-wave P1h gather
// streams, putting ~L2-latency weight loads on every wave's serial chain and
// making per-wave stall grow with occupancy. Fix: block loads wsh+tbf+R1h into
// LDS once (1 barrier), weight reads become fixed-latency conflict-free
// ds_read_b128. LDS stage for the gather is deleted: lanes gather P1h directly
// in B-frag layout (16B at [row][ks*16+hv*8] — verified identical indexing).
// LDS 26 KB/block -> 6 blocks/CU; launch_bounds(256,6) targets <=85 VGPR.
__global__ __launch_bounds__(256, 6) void uv_main(
    const int*   __restrict__ huv,
    const int*   __restrict__ hr,
    const _Float16* __restrict__ P1h,
    const float* __restrict__ UB,
    const _Float16* __restrict__ wsh,
    const float* __restrict__ tbf,
    float*       __restrict__ out) {
    __shared__ _Float16 lw[12288];           // 24 KB: w2(pi) | wa1low | wa2 frags
    __shared__ float    ltb[192];            // b2p | ba2p | wa3p
    __shared__ _Float16 lr1[320];            // R1h[5][64]
    const int tid = threadIdx.x;

    // ---- cooperative one-shot load of all shared tables (then 1 barrier)
    {
        const uint4* src = (const uint4*)wsh;  // 1536 uint4
        uint4* dst = (uint4*)lw;
        #pragma unroll
        for (int i = 0; i < 6; ++i) dst[tid + 256*i] = src[tid + 256*i];
        if (tid < 48) ((uint4*)ltb)[tid] = ((const uint4*)tbf)[tid];
        if (tid < 40) ((uint4*)lr1)[tid] = ((const uint4*)(tbf + 192))[tid];
    }
    __syncthreads();

    const int lane = tid & 63;
    const int w = tid >> 6;
    const int b = blockIdx.x * 4 + w;        // node id (4 independent waves)
    const int n = lane & 31, hv = lane >> 5;

    #define G8(base, f) (*(const half8*)(lw + (base) + ((f)*64 + lane)*8))

    // ---- direct gather: lane owns tokens n (nt=0) and t1 (nt=1)
    const int t1   = (32 + n < LH) ? 32 + n : LH - 1;
    const int row0 = huv[b*LH + n];
    const int row1 = huv[b*LH + t1];
    const int ir0  = hr[b*LH + n];
    const int ir1  = hr[b*LH + t1];

    half8 bf[2][4];                          // B-frags of H = relu(P1 + R1)
    #pragma unroll
    for (int ks = 0; ks < 4; ++ks) {
        half8 p0 = *(const half8*)(P1h + (size_t)row0*64 + ks*16 + hv*8);
        half8 p1 = *(const half8*)(P1h + (size_t)row1*64 + ks*16 + hv*8);
        half8 r0 = *(const half8*)(lr1 + ir0*64 + ks*16 + hv*8);
        half8 r1 = *(const half8*)(lr1 + ir1*64 + ks*16 + hv*8);
        bf[0][ks] = addrelu8(p0, r0);
        bf[1][ks] = addrelu8(p1, r1);
    }

    // ======== layer 2 (mt-sequential): O = W2^T(pi) @ H + b2
    half8 of[2][4];                          // O frags: feed att1 AND the epilogue
    #pragma unroll
    for (int mt = 0; mt < 2; ++mt) {
        f32x16 a0 = ldbias(ltb, hv, mt);
        f32x16 a1 = ldbias(ltb, hv, mt);
        #pragma unroll
        for (int ks = 0; ks < 4; ++ks) {
            half8 wv = G8(0, mt*4 + ks);
            a0 = MFMA(wv, bf[0][ks], a0);
            a1 = MFMA(wv, bf[1][ks], a1);
        }
        xform_tile(a0, hv, of[0][mt*2], of[0][mt*2 + 1]);
        xform_tile(a1, hv, of[1][mt*2], of[1][mt*2 + 1]);
    }

    // ======== att1 (mt-sequential): A1 = relu(Wa1low^T @ O + UB[node])
    const float* ubrow = UB + (size_t)b * 64;    // wave-uniform -> broadcast reads
    half8 af[2][4];
    #pragma unroll
    for (int mt = 0; mt < 2; ++mt) {
        f32x16 a0 = ldbias(ubrow, hv, mt);
        f32x16 a1 = ldbias(ubrow, hv, mt);
        #pragma unroll
        for (int ks = 0; ks < 4; ++ks) {
            half8 wv = G8(4096, mt*4 + ks);
            a0 = MFMA(wv, of[0][ks], a0);
            a1 = MFMA(wv, of[1][ks], a1);
        }
        xform_tile(a0, hv, af[0][mt*2], af[0][mt*2 + 1]);
        xform_tile(a1, hv, af[1][mt*2], af[1][mt*2 + 1]);
    }

    // ======== att2 + logits (mt-sequential; bias via MFMA C)
    float lg0 = 0.f, lg1 = 0.f;
    #pragma unroll
    for (int mt = 0; mt < 2; ++mt) {
        f32x16 c0, c1v;
        {
            const f32x16 bc = ldbias(ltb + 64, hv, mt);
            half8 wv = G8(8192, mt*4 + 0);
            c0  = MFMA(wv, af[0][0], bc);
            c1v = MFMA(wv, af[1][0], bc);
        }
        #pragma unroll
        for (int ks = 1; ks < 4; ++ks) {
            half8 wv = G8(8192, mt*4 + ks);
            c0  = MFMA(wv, af[0][ks], c0);
            c1v = MFMA(wv, af[1][ks], c1v);
        }
        #pragma unroll
        for (int q = 0; q < 4; ++q) {
            float4 w3 = ((const float4*)(ltb + 128))[hv*8 + mt*4 + q];
            lg0 += fmaxf(c0[4*q], 0.f)*w3.x + fmaxf(c0[4*q+1], 0.f)*w3.y
                 + fmaxf(c0[4*q+2], 0.f)*w3.z + fmaxf(c0[4*q+3], 0.f)*w3.w;
            lg1 += fmaxf(c1v[4*q], 0.f)*w3.x + fmaxf(c1v[4*q+1], 0.f)*w3.y
                 + fmaxf(c1v[4*q+2], 0.f)*w3.z + fmaxf(c1v[4*q+3], 0.f)*w3.w;
        }
    }
    // combine feat-halves across lane^32: lane holds logits of tokens n, n+32
    lg0 += __shfl_xor(lg0, 32, 64);
    lg1 += __shfl_xor(lg1, 32, 64);
    if (32 + n >= LH) lg1 = -1e30f;

    // ---- softmax over 64 tokens (butterfly over the 32 token-lanes)
    float mx = fmaxf(lg0, lg1);
    #pragma unroll
    for (int off = 16; off >= 1; off >>= 1) mx = fmaxf(mx, __shfl_xor(mx, off, 64));
    const float e0 = __expf(lg0 - mx);
    const float e1 = __expf(lg1 - mx);       // masked token: exp(-huge)=0
    float s = e0 + e1;
    #pragma unroll
    for (int off = 16; off >= 1; off >>= 1) s += __shfl_xor(s, off, 64);
    const float at0 = e0 / s, at1 = e1 / s;

    // ======== epilogue: out[feat] = sum_tok att[tok]*O[feat][tok]
    float cur[32];
    #pragma unroll
    for (int ks = 0; ks < 4; ++ks)
        #pragma unroll
        for (int j = 0; j < 8; ++j)
            cur[ks*8 + j] = at0 * (float)of[0][ks][j] + at1 * (float)of[1][ks][j];
    #pragma unroll
    for (int k = 0; k < 5; ++k) {
        const int d = 1 << k, mybit = (lane >> k) & 1, half = 16 >> k;
        #pragma unroll
        for (int j2 = 0; j2 < 16; ++j2) {
            if (j2 < half) {
                float sel  = mybit ? cur[2*j2]     : cur[2*j2 + 1];
                float got  = __shfl_xor(sel, d, 64);
                float keep = mybit ? cur[2*j2 + 1] : cur[2*j2];
                cur[j2] = keep + got;
            }
        }
    }
    const int feat = ((lane >> 3) & 3)*16 + hv*8 + (lane & 7);
    __builtin_nontemporal_store(cur[0], out + (size_t)b * D + feat);
    #undef G8
}

extern "C" void kernel_launch(void* const* d_in, const int* in_sizes, int n_in,
                              void* d_out, int out_size, void* d_ws, size_t ws_size,
                              hipStream_t stream) {
    const int*   nodes      = (const int*)  d_in[0];
    const int*   history_uv = (const int*)  d_in[1];
    const int*   history_r  = (const int*)  d_in[2];
    const float* v2e        = (const float*)d_in[3];
    const float* u2e        = (const float*)d_in[4];
    const float* r2e        = (const float*)d_in[5];
    const float* w1         = (const float*)d_in[6];
    const float* b1         = (const float*)d_in[7];
    const float* w2         = (const float*)d_in[8];
    const float* b2         = (const float*)d_in[9];
    const float* wa1        = (const float*)d_in[10];
    const float* ba1        = (const float*)d_in[11];
    const float* wa2        = (const float*)d_in[12];
    const float* ba2        = (const float*)d_in[13];
    const float* wa3        = (const float*)d_in[14];
    float* out = (float*)d_out;

    _Float16* wsh = (_Float16*)d_ws;
    float*    tbf = (float*)((char*)d_ws + TBF_OFF);
    float*    UB  = (float*)((char*)d_ws + UB_OFF);
    _Float16* P1h = (_Float16*)((char*)d_ws + P1_OFF);

    prep_all<<<960, 256, 0, stream>>>(nodes, v2e, u2e, r2e, w1, b1, w2, b2,
                                      wa1, ba1, wa2, ba2, wa3, wsh, tbf, UB, P1h);
    uv_main<<<NB/4, 256, 0, stream>>>(history_uv, history_r,
                                      P1h, UB, wsh, tbf, out);
}

// Round 7
// 170.404 us; speedup vs baseline: 1.4686x; 1.4686x over previous
//
#include <hip/hip_runtime.h>
#include <math.h>

#define NB 16384
#define LH 50
#define D  64

// workspace layout (bytes):
//   0       : wsh  (f16 weight frags, 3 sections x 4096 halves = 24 KB)
//   49152   : tbf  (f32: b2p[64] ba2p[64] wa3p[64] | R1h f16[5][64] @ f32-idx 192)
//   65536   : UB   (f32 [16384][64] permuted, u@A1up + ba1, per node)
//   4259840 : P1h  (f16 [100000][64] permuted slot order, v2e@W1_top)
#define TBF_OFF 49152
#define UB_OFF  65536
#define P1_OFF  4259840

typedef _Float16 half2v __attribute__((ext_vector_type(2)));
typedef _Float16 half8  __attribute__((ext_vector_type(8)));
typedef float    f32x16 __attribute__((ext_vector_type(16)));
typedef unsigned int u32;

#define MFMA(a, b, c) __builtin_amdgcn_mfma_f32_32x32x16_f16((a), (b), (c), 0, 0, 0)

// ---- fragment facts (32x32x16, verified) ----
// A[m][k]: m=lane&31, k=(lane>>5)*8+j (8 contiguous k per lane)
// B[k][n]: n=lane&31, k=(lane>>5)*8+j
// C/D:     col=lane&31, row=(reg&3)+8*(reg>>2)+4*(lane>>5)
// permuted slot t(hv,mt,q) = hv*32+mt*16+q <-> feat = mt*32+(q&3)+8*(q>>2)+4*hv

__device__ __forceinline__ u32 pack2(float a, float b) {
    half2v h; h[0] = (_Float16)a; h[1] = (_Float16)b;
    return __builtin_bit_cast(u32, h);
}
__device__ __forceinline__ half8 mk8(u32 a, u32 b, u32 c, u32 d) {
    uint4 t = make_uint4(a, b, c, d);
    return __builtin_bit_cast(half8, t);
}
__device__ __forceinline__ half8 cvt8(const float* __restrict__ p) {
    float4 u = *(const float4*)p;
    float4 v = *(const float4*)(p + 4);
    return mk8(pack2(u.x, u.y), pack2(u.z, u.w), pack2(v.x, v.y), pack2(v.z, v.w));
}
// f16 add + relu (compiles to v_pk_add_f16 / v_pk_max_f16)
__device__ __forceinline__ half8 addrelu8(half8 a, half8 r) {
    half8 s = a + r;
    #pragma unroll
    for (int j = 0; j < 8; ++j) s[j] = s[j] > (_Float16)0 ? s[j] : (_Float16)0;
    return s;
}

// relu + f16-pack + lane^32 exchange: one C tile -> two B-frags (k-halves)
__device__ __forceinline__ void xform_tile(const f32x16& t, int hv, half8& f0, half8& f1) {
    u32 p[8], rp[8];
    #pragma unroll
    for (int q = 0; q < 8; ++q) p[q] = pack2(fmaxf(t[2*q], 0.f), fmaxf(t[2*q+1], 0.f));
    #pragma unroll
    for (int q = 0; q < 8; ++q) rp[q] = (u32)__shfl_xor((int)p[q], 32, 64);
    f0 = hv ? mk8(rp[2], rp[3], p[2], p[3]) : mk8(p[0], p[1], rp[0], rp[1]);
    f1 = hv ? mk8(rp[6], rp[7], p[6], p[7]) : mk8(p[4], p[5], rp[4], rp[5]);
}

// bias/UB tile from a 64-float permuted row (works for LDS or global pointers)
__device__ __forceinline__ f32x16 ldbias(const float* tb, int hv, int mt) {
    const float4* p = (const float4*)tb + hv*8 + mt*4;
    f32x16 r;
    #pragma unroll
    for (int q = 0; q < 4; ++q) {
        float4 v = p[q];
        r[4*q] = v.x; r[4*q+1] = v.y; r[4*q+2] = v.z; r[4*q+3] = v.w;
    }
    return r;
}

// build an A-frag of a 64x64 row-major f32 weight W on the fly (L1/L2-hot)
__device__ __forceinline__ half8 mkw(const float* __restrict__ W, int ks, int mt,
                                     int hv, int m) {
    half8 r;
    #pragma unroll
    for (int j = 0; j < 8; ++j)
        r[j] = (_Float16)W[(ks*16 + hv*8 + j)*64 + mt*32 + m];
    return r;
}

// ================= K1: ALL prep in one launch (block-range partitioned) ========
// blocks [0,782)   : P1h = f16(v2e @ W1_top)   (w1-top frags converted inline)
// blocks [782,910) : UB  = u2e[nodes]@A1up+ba1 (wa1-up frags converted inline)
// blocks [910,958) : wsh sections 0..2 (w2 pi-folded, wa1low, wa2)
// block  958       : tbf tables b2p/ba2p/wa3p
// block  959       : R1h[5][64] f16 (rating rows through layer1, f32 math)
__global__ __launch_bounds__(256) void prep_all(
    const int*   __restrict__ nodes,
    const float* __restrict__ v2e, const float* __restrict__ u2e,
    const float* __restrict__ r2e,
    const float* __restrict__ w1,  const float* __restrict__ b1,
    const float* __restrict__ w2,  const float* __restrict__ b2,
    const float* __restrict__ wa1, const float* __restrict__ ba1,
    const float* __restrict__ wa2, const float* __restrict__ ba2,
    const float* __restrict__ wa3,
    _Float16* __restrict__ wsh, float* __restrict__ tbf,
    float* __restrict__ UB, _Float16* __restrict__ P1h) {
    const int blk = blockIdx.x;
    const int lane = threadIdx.x & 63;
    const int n = lane & 31, hv = lane >> 5;

    if (blk < 782) {                               // ---- P1h tiles (f16 rows)
        const int tile = blk*4 + (threadIdx.x >> 6);
        if (tile >= 3125) return;
        const int item = tile*32 + n;
        half8 bf[4];
        #pragma unroll
        for (int ks = 0; ks < 4; ++ks)
            bf[ks] = cvt8(v2e + (size_t)item*64 + ks*16 + hv*8);
        f32x16 a0, a1;
        #pragma unroll
        for (int q = 0; q < 16; ++q) { a0[q] = 0.f; a1[q] = 0.f; }
        #pragma unroll
        for (int ks = 0; ks < 4; ++ks) {
            a0 = MFMA(mkw(w1, ks, 0, hv, n), bf[ks], a0);
            a1 = MFMA(mkw(w1, ks, 1, hv, n), bf[ks], a1);
        }
        u32 dw[16];
        #pragma unroll
        for (int q = 0; q < 8; ++q) dw[q]     = pack2(a0[2*q], a0[2*q+1]);
        #pragma unroll
        for (int q = 0; q < 8; ++q) dw[8 + q] = pack2(a1[2*q], a1[2*q+1]);
        uint4* dst = (uint4*)(P1h + (size_t)item*64 + hv*32);
        dst[0] = make_uint4(dw[0],  dw[1],  dw[2],  dw[3]);
        dst[1] = make_uint4(dw[4],  dw[5],  dw[6],  dw[7]);
        dst[2] = make_uint4(dw[8],  dw[9],  dw[10], dw[11]);
        dst[3] = make_uint4(dw[12], dw[13], dw[14], dw[15]);
        return;
    }
    if (blk < 910) {                               // ---- UB tiles
        const int tile = (blk - 782)*4 + (threadIdx.x >> 6);   // 512 tiles exactly
        const int s = tile*32 + n;
        const int nid = nodes[s];
        half8 bf[4];
        #pragma unroll
        for (int ks = 0; ks < 4; ++ks)
            bf[ks] = cvt8(u2e + (size_t)nid*64 + ks*16 + hv*8);
        f32x16 a0, a1;
        #pragma unroll
        for (int q = 0; q < 16; ++q) {
            a0[q] = ba1[(q & 3) + 8*(q >> 2) + 4*hv];
            a1[q] = ba1[32 + (q & 3) + 8*(q >> 2) + 4*hv];
        }
        const float* wup = wa1 + 64*64;            // wa1 upper half rows
        #pragma unroll
        for (int ks = 0; ks < 4; ++ks) {
            a0 = MFMA(mkw(wup, ks, 0, hv, n), bf[ks], a0);
            a1 = MFMA(mkw(wup, ks, 1, hv, n), bf[ks], a1);
        }
        float4* dst = (float4*)(UB + (size_t)s*64 + hv*32);
        #pragma unroll
        for (int q = 0; q < 4; ++q) {
            dst[q]     = make_float4(a0[4*q], a0[4*q+1], a0[4*q+2], a0[4*q+3]);
            dst[4 + q] = make_float4(a1[4*q], a1[4*q+1], a1[4*q+2], a1[4*q+3]);
        }
        return;
    }
    if (blk < 958) {                               // ---- wsh sections 0..2
        const int idx = (blk - 910)*256 + threadIdx.x;         // [0, 12288)
        const int j = idx & 7, l2 = (idx >> 3) & 63;
        const int hv2 = l2 >> 5, m31 = l2 & 31;
        const int f = (idx >> 9) & 7, ks = f & 3, mt = f >> 2;
        const int sec = idx >> 12;
        const int tau = ks*16 + hv2*8 + j;
        float v;
        if (sec == 0) {       // w2 with k-permutation folded in
            const int thv = (tau >> 5) & 1, tmt = (tau >> 4) & 1, i = tau & 15;
            const int feat = tmt*32 + (i & 3) + 8*(i >> 2) + 4*thv;
            v = w2[feat*64 + mt*32 + m31];
        }
        else if (sec == 1) v = wa1[tau*64 + mt*32 + m31];
        else               v = wa2[tau*64 + mt*32 + m31];
        wsh[idx] = (_Float16)v;
        return;
    }
    if (blk == 958) {                              // ---- tbf tables
        if (threadIdx.x < 64) {
            const int t = threadIdx.x;
            const int thv = t >> 5, r = t & 31, mtt = r >> 4, i = r & 15;
            const int feat = mtt*32 + (i & 3) + 8*(i >> 2) + 4*thv;
            tbf[t]       = b2[feat];
            tbf[64 + t]  = ba2[feat];
            tbf[128 + t] = wa3[feat];
        }
        return;
    }
    {                                              // ---- blk 959: R1h (f16)
        _Float16* R1h = (_Float16*)(tbf + 192);
        #pragma unroll 1
        for (int base = 0; base < 320; base += 256) {
            const int o = base + (int)threadIdx.x;
            if (o < 320) {
                const int rr = o >> 6, tt = o & 63;
                const int thv = tt >> 5, r5 = tt & 31, mtt = r5 >> 4, i = r5 & 15;
                const int feat = mtt*32 + (i & 3) + 8*(i >> 2) + 4*thv;
                float acc = b1[feat];
                for (int k = 0; k < 64; ++k)
                    acc += r2e[rr*64 + k] * w1[(64 + k)*64 + feat];
                R1h[rr*64 + tt] = (_Float16)acc;
            }
        }
    }
}

// ================= K2: fused forward — weights in LDS, direct B-frag gather ====
// R6 retry with the spill fixed: launch_bounds(256,4) (R5-proven allocation,
// 64 VGPR no-spill) instead of (256,6) which forced 15 KB/wave scratch traffic
// (WRITE_SIZE 242 MB). lr1 rows padded to 72 halves (144 B) so the 5 rating
// rows hit distinct LDS bank groups (R6: 128 B stride -> 937K conflicts).
// LDS 26.4 KB; occupancy target 4 waves/SIMD (~50%).
__global__ __launch_bounds__(256, 4) void uv_main(
    const int*   __restrict__ huv,
    const int*   __restrict__ hr,
    const _Float16* __restrict__ P1h,
    const float* __restrict__ UB,
    const _Float16* __restrict__ wsh,
    const float* __restrict__ tbf,
    float*       __restrict__ out) {
    __shared__ _Float16 lw[12288];           // 24 KB: w2(pi) | wa1low | wa2 frags
    __shared__ float    ltb[192];            // b2p | ba2p | wa3p
    __shared__ _Float16 lr1[5*72];           // R1h rows, 72-half stride (bank-spread)
    const int tid = threadIdx.x;

    // ---- cooperative one-shot load of all shared tables (then 1 barrier)
    {
        const uint4* src = (const uint4*)wsh;  // 1536 uint4
        uint4* dst = (uint4*)lw;
        #pragma unroll
        for (int i = 0; i < 6; ++i) dst[tid + 256*i] = src[tid + 256*i];
        if (tid < 48) ((uint4*)ltb)[tid] = ((const uint4*)tbf)[tid];
        if (tid < 40) {                       // re-stride 64->72 halves (16B-aligned)
            const int r = tid >> 3, q = tid & 7;
            ((uint4*)lr1)[r*9 + q] = ((const uint4*)(tbf + 192))[tid];
        }
    }
    __syncthreads();

    const int lane = tid & 63;
    const int w = tid >> 6;
    const int b = blockIdx.x * 4 + w;        // node id (4 independent waves)
    const int n = lane & 31, hv = lane >> 5;

    #define G8(base, f) (*(const half8*)(lw + (base) + ((f)*64 + lane)*8))

    // ---- direct gather: lane owns tokens n (nt=0) and t1 (nt=1)
    const int t1   = (32 + n < LH) ? 32 + n : LH - 1;
    const int row0 = huv[b*LH + n];
    const int row1 = huv[b*LH + t1];
    const int ir0  = hr[b*LH + n];
    const int ir1  = hr[b*LH + t1];

    half8 bf[2][4];                          // B-frags of H = relu(P1 + R1)
    #pragma unroll
    for (int ks = 0; ks < 4; ++ks) {
        half8 p0 = *(const half8*)(P1h + (size_t)row0*64 + ks*16 + hv*8);
        half8 p1 = *(const half8*)(P1h + (size_t)row1*64 + ks*16 + hv*8);
        half8 r0 = *(const half8*)(lr1 + ir0*72 + ks*16 + hv*8);
        half8 r1 = *(const half8*)(lr1 + ir1*72 + ks*16 + hv*8);
        bf[0][ks] = addrelu8(p0, r0);
        bf[1][ks] = addrelu8(p1, r1);
    }

    // ======== layer 2 (mt-sequential): O = W2^T(pi) @ H + b2
    half8 of[2][4];                          // O frags: feed att1 AND the epilogue
    #pragma unroll
    for (int mt = 0; mt < 2; ++mt) {
        f32x16 a0 = ldbias(ltb, hv, mt);
        f32x16 a1 = ldbias(ltb, hv, mt);
        #pragma unroll
        for (int ks = 0; ks < 4; ++ks) {
            half8 wv = G8(0, mt*4 + ks);
            a0 = MFMA(wv, bf[0][ks], a0);
            a1 = MFMA(wv, bf[1][ks], a1);
        }
        xform_tile(a0, hv, of[0][mt*2], of[0][mt*2 + 1]);
        xform_tile(a1, hv, of[1][mt*2], of[1][mt*2 + 1]);
    }

    // ======== att1 (mt-sequential): A1 = relu(Wa1low^T @ O + UB[node])
    const float* ubrow = UB + (size_t)b * 64;    // wave-uniform -> broadcast reads
    half8 af[2][4];
    #pragma unroll
    for (int mt = 0; mt < 2; ++mt) {
        f32x16 a0 = ldbias(ubrow, hv, mt);
        f32x16 a1 = ldbias(ubrow, hv, mt);
        #pragma unroll
        for (int ks = 0; ks < 4; ++ks) {
            half8 wv = G8(4096, mt*4 + ks);
            a0 = MFMA(wv, of[0][ks], a0);
            a1 = MFMA(wv, of[1][ks], a1);
        }
        xform_tile(a0, hv, af[0][mt*2], af[0][mt*2 + 1]);
        xform_tile(a1, hv, af[1][mt*2], af[1][mt*2 + 1]);
    }

    // ======== att2 + logits (mt-sequential; bias via MFMA C)
    float lg0 = 0.f, lg1 = 0.f;
    #pragma unroll
    for (int mt = 0; mt < 2; ++mt) {
        f32x16 c0, c1v;
        {
            const f32x16 bc = ldbias(ltb + 64, hv, mt);
            half8 wv = G8(8192, mt*4 + 0);
            c0  = MFMA(wv, af[0][0], bc);
            c1v = MFMA(wv, af[1][0], bc);
        }
        #pragma unroll
        for (int ks = 1; ks < 4; ++ks) {
            half8 wv = G8(8192, mt*4 + ks);
            c0  = MFMA(wv, af[0][ks], c0);
            c1v = MFMA(wv, af[1][ks], c1v);
        }
        #pragma unroll
        for (int q = 0; q < 4; ++q) {
            float4 w3 = ((const float4*)(ltb + 128))[hv*8 + mt*4 + q];
            lg0 += fmaxf(c0[4*q], 0.f)*w3.x + fmaxf(c0[4*q+1], 0.f)*w3.y
                 + fmaxf(c0[4*q+2], 0.f)*w3.z + fmaxf(c0[4*q+3], 0.f)*w3.w;
            lg1 += fmaxf(c1v[4*q], 0.f)*w3.x + fmaxf(c1v[4*q+1], 0.f)*w3.y
                 + fmaxf(c1v[4*q+2], 0.f)*w3.z + fmaxf(c1v[4*q+3], 0.f)*w3.w;
        }
    }
    // combine feat-halves across lane^32: lane holds logits of tokens n, n+32
    lg0 += __shfl_xor(lg0, 32, 64);
    lg1 += __shfl_xor(lg1, 32, 64);
    if (32 + n >= LH) lg1 = -1e30f;

    // ---- softmax over 64 tokens (butterfly over the 32 token-lanes)
    float mx = fmaxf(lg0, lg1);
    #pragma unroll
    for (int off = 16; off >= 1; off >>= 1) mx = fmaxf(mx, __shfl_xor(mx, off, 64));
    const float e0 = __expf(lg0 - mx);
    const float e1 = __expf(lg1 - mx);       // masked token: exp(-huge)=0
    float s = e0 + e1;
    #pragma unroll
    for (int off = 16; off >= 1; off >>= 1) s += __shfl_xor(s, off, 64);
    const float at0 = e0 / s, at1 = e1 / s;

    // ======== epilogue: out[feat] = sum_tok att[tok]*O[feat][tok]
    float cur[32];
    #pragma unroll
    for (int ks = 0; ks < 4; ++ks)
        #pragma unroll
        for (int j = 0; j < 8; ++j)
            cur[ks*8 + j] = at0 * (float)of[0][ks][j] + at1 * (float)of[1][ks][j];
    #pragma unroll
    for (int k = 0; k < 5; ++k) {
        const int d = 1 << k, mybit = (lane >> k) & 1, half = 16 >> k;
        #pragma unroll
        for (int j2 = 0; j2 < 16; ++j2) {
            if (j2 < half) {
                float sel  = mybit ? cur[2*j2]     : cur[2*j2 + 1];
                float got  = __shfl_xor(sel, d, 64);
                float keep = mybit ? cur[2*j2 + 1] : cur[2*j2];
                cur[j2] = keep + got;
            }
        }
    }
    const int feat = ((lane >> 3) & 3)*16 + hv*8 + (lane & 7);
    __builtin_nontemporal_store(cur[0], out + (size_t)b * D + feat);
    #undef G8
}

extern "C" void kernel_launch(void* const* d_in, const int* in_sizes, int n_in,
                              void* d_out, int out_size, void* d_ws, size_t ws_size,
                              hipStream_t stream) {
    const int*   nodes      = (const int*)  d_in[0];
    const int*   history_uv = (const int*)  d_in[1];
    const int*   history_r  = (const int*)  d_in[2];
    const float* v2e        = (const float*)d_in[3];
    const float* u2e        = (const float*)d_in[4];
    const float* r2e        = (const float*)d_in[5];
    const float* w1         = (const float*)d_in[6];
    const float* b1         = (const float*)d_in[7];
    const float* w2         = (const float*)d_in[8];
    const float* b2         = (const float*)d_in[9];
    const float* wa1        = (const float*)d_in[10];
    const float* ba1        = (const float*)d_in[11];
    const float* wa2        = (const float*)d_in[12];
    const float* ba2        = (const float*)d_in[13];
    const float* wa3        = (const float*)d_in[14];
    float* out = (float*)d_out;

    _Float16* wsh = (_Float16*)d_ws;
    float*    tbf = (float*)((char*)d_ws + TBF_OFF);
    float*    UB  = (float*)((char*)d_ws + UB_OFF);
    _Float16* P1h = (_Float16*)((char*)d_ws + P1_OFF);

    prep_all<<<960, 256, 0, stream>>>(nodes, v2e, u2e, r2e, w1, b1, w2, b2,
                                      wa1, ba1, wa2, ba2, wa3, wsh, tbf, UB, P1h);
    uv_main<<<NB/4, 256, 0, stream>>>(history_uv, history_r,
                                      P1h, UB, wsh, tbf, out);
}